// Round 3
// baseline (133.798 us; speedup 1.0000x reference)
//
#include <hip/hip_runtime.h>
#include <hip/hip_bf16.h>
#include <stdint.h>

// Problem constants
#define Bb  2
#define Ss  2048
#define Hh  768
#define NHh 12
#define HDd 64

typedef short bf16x8 __attribute__((ext_vector_type(8)));
typedef float f32x4  __attribute__((ext_vector_type(4)));
typedef unsigned short u16x4 __attribute__((ext_vector_type(4)));

// f32 -> bf16 round-to-nearest-even
__device__ __forceinline__ unsigned short f2bf(float x) {
    union { float f; unsigned int u; } v; v.f = x;
    unsigned int r = v.u + 0x7fffu + ((v.u >> 16) & 1u);
    return (unsigned short)(r >> 16);
}

// async global->LDS, 16B per lane (LDS dest = wave-uniform base + lane*16)
__device__ __forceinline__ void gl_lds16(const unsigned short* g, unsigned short* l) {
    __builtin_amdgcn_global_load_lds(
        (const __attribute__((address_space(1))) unsigned int*)g,
        (__attribute__((address_space(3))) unsigned int*)l, 16, 0, 0);
}

// Swizzled fragment read: tile rows are 64 bf16 (128B = 8 chunks of 16B).
// Stage wrote global chunk (row, seg^(row&7)) at linear slot (row, seg);
// reading slot s^(row&7) returns global chunk (row, s). Banks: 16 lanes
// (rows) spread over 8 chunk slots -> 2-way conflict (free) instead of 16.
__device__ __forceinline__ bf16x8 ldfrag(const unsigned short* lds, int row, int s) {
    return *(const bf16x8*)&lds[(row << 6) + ((s ^ (row & 7)) << 3)];
}

// ---------------------------------------------------------------------------
// Cast hs [4096x768], Wq [768x768], Wk [768x768] f32 -> bf16.
// ---------------------------------------------------------------------------
__global__ __launch_bounds__(256)
void cast_kernel(const float* __restrict__ hs, const float* __restrict__ Wq,
                 const float* __restrict__ Wk,
                 unsigned short* __restrict__ hsb, unsigned short* __restrict__ Wqb,
                 unsigned short* __restrict__ Wkb)
{
    int cid = blockIdx.x * 256 + threadIdx.x;      // 0 .. 540671
    const float* src; unsigned short* dst; int base;
    if (cid < 393216)      { src = hs; dst = hsb; base = cid; }
    else if (cid < 466944) { src = Wq; dst = Wqb; base = cid - 393216; }
    else                   { src = Wk; dst = Wkb; base = cid - 466944; }
    float4 a0 = ((const float4*)src)[(size_t)base * 2];
    float4 a1 = ((const float4*)src)[(size_t)base * 2 + 1];
    bf16x8 v;
    v[0] = (short)f2bf(a0.x); v[1] = (short)f2bf(a0.y);
    v[2] = (short)f2bf(a0.z); v[3] = (short)f2bf(a0.w);
    v[4] = (short)f2bf(a1.x); v[5] = (short)f2bf(a1.y);
    v[6] = (short)f2bf(a1.z); v[7] = (short)f2bf(a1.w);
    ((bf16x8*)dst)[base] = v;
}

// ---------------------------------------------------------------------------
// Projection: Out[m,n] = sum_k hsb[m,k]*Wb[n,k] + bias[n]  (bf16 out).
// Tile 64(M) x 128(N), BK=64 -> grid (64,6,2) = 768 blocks = exactly 3/CU.
// Operands swapped (A=W rows) so acc reg axis = output cols -> ushort4 store.
// Staging via global_load_lds with pre-swizzled source; swizzled frag reads.
// ---------------------------------------------------------------------------
__global__ __launch_bounds__(256)
void proj_kernel(const unsigned short* __restrict__ hsb,
                 const unsigned short* __restrict__ Wqb,
                 const unsigned short* __restrict__ Wkb,
                 const float* __restrict__ bq, const float* __restrict__ bk,
                 unsigned short* __restrict__ Qb, unsigned short* __restrict__ Kb)
{
    const int zq = blockIdx.z;
    const unsigned short* __restrict__ Wb = zq ? Wkb : Wqb;
    const float* __restrict__ bias = zq ? bk : bq;
    unsigned short* __restrict__ Out = zq ? Kb : Qb;

    const int m0 = blockIdx.x * 64;                // hs-row tile (output rows)
    const int n0 = blockIdx.y * 128;               // W-row tile (output cols)

    __shared__ unsigned short As[64 * 64];         // hs rows [row][k]
    __shared__ unsigned short Bs[128 * 64];        // W rows  [row][k]

    const int tid  = threadIdx.x;
    const int lane = tid & 63;
    const int w    = tid >> 6;
    const int wc   = (w & 1) * 64;                 // wave's output-col origin
    const int wr   = (w >> 1) * 32;                // wave's output-row origin
    const int lg   = lane >> 4;
    const int l15  = lane & 15;

    f32x4 acc[4][2] = {};

    for (int k0 = 0; k0 < Hh; k0 += 64) {
        #pragma unroll
        for (int i = 0; i < 2; ++i) {              // A: 512 chunks
            int cc = i * 256 + tid, row = cc >> 3, seg = cc & 7;
            gl_lds16(hsb + (size_t)(m0 + row) * Hh + k0 + ((seg ^ (row & 7)) << 3),
                     &As[cc * 8]);
        }
        #pragma unroll
        for (int i = 0; i < 4; ++i) {              // B: 1024 chunks
            int cc = i * 256 + tid, row = cc >> 3, seg = cc & 7;
            gl_lds16(Wb + (size_t)(n0 + row) * Hh + k0 + ((seg ^ (row & 7)) << 3),
                     &Bs[cc * 8]);
        }
        __syncthreads();

        #pragma unroll
        for (int kk = 0; kk < 2; ++kk) {
            const int s = kk * 4 + lg;
            bf16x8 wf[4], hf[2];
            #pragma unroll
            for (int i = 0; i < 4; ++i) wf[i] = ldfrag(Bs, wc + i * 16 + l15, s);
            #pragma unroll
            for (int j = 0; j < 2; ++j) hf[j] = ldfrag(As, wr + j * 16 + l15, s);
            #pragma unroll
            for (int i = 0; i < 4; ++i)
                #pragma unroll
                for (int j = 0; j < 2; ++j)
                    acc[i][j] = __builtin_amdgcn_mfma_f32_16x16x32_bf16(
                        wf[i], hf[j], acc[i][j], 0, 0, 0);
        }
        __syncthreads();
    }

    #pragma unroll
    for (int i = 0; i < 4; ++i) {
        const int nb = n0 + wc + i * 16 + lg * 4;
        const float4 bv = *(const float4*)&bias[nb];
        #pragma unroll
        for (int j = 0; j < 2; ++j) {
            const int m = m0 + wr + j * 16 + l15;
            u16x4 o;
            o[0] = f2bf(acc[i][j][0] + bv.x);
            o[1] = f2bf(acc[i][j][1] + bv.y);
            o[2] = f2bf(acc[i][j][2] + bv.z);
            o[3] = f2bf(acc[i][j][3] + bv.w);
            *(u16x4*)&Out[(size_t)m * Hh + nb] = o;
        }
    }
}

// ---------------------------------------------------------------------------
// Scores: out[b,q,h,k] = relu( (Q_h[q,:].K_h[k,:]) / 8 + mask[b,q] )
// 1D grid 6144, XCD-chunked: 3 heads per XCD so each head's Q+K (1 MB) stays
// resident in that XCD's 4 MB L2 (kills ~8x cross-XCD fetch replication).
// Operands swapped (A=K rows) so acc reg axis = 4 consecutive k -> float4.
// ---------------------------------------------------------------------------
__global__ __launch_bounds__(256)
void score_kernel(const unsigned short* __restrict__ Qb,
                  const unsigned short* __restrict__ Kb,
                  const float* __restrict__ mask,
                  float* __restrict__ out)
{
    // XCD-aware decode: 6144 blocks, 8 XCDs, 768 per XCD = 3 heads x 256.
    const int bid = blockIdx.x;
    const int gid = (bid & 7) * 768 + (bid >> 3);
    const int bh  = gid >> 8;                      // 0..23  (b*NH + h)
    const int rem = gid & 255;
    const int c0  = (rem >> 4) * 128;              // key-tile origin
    const int q0  = (rem & 15) * 128;              // query-tile origin
    const int b   = bh / NHh, h = bh % NHh;

    __shared__ unsigned short Qs[128 * 64];
    __shared__ unsigned short Ks[128 * 64];

    const int tid  = threadIdx.x;
    const int lane = tid & 63;
    const int w    = tid >> 6;
    const int wm   = (w >> 1) * 64;                // K-side (out cols)
    const int wn   = (w & 1) * 64;                 // Q-side (out rows)
    const int lg   = lane >> 4;
    const int l15  = lane & 15;

    #pragma unroll
    for (int i = 0; i < 4; ++i) {
        int cc = i * 256 + tid, row = cc >> 3, seg = cc & 7;
        const int sg = (seg ^ (row & 7)) << 3;
        gl_lds16(Qb + (size_t)(b * Ss + q0 + row) * Hh + h * HDd + sg, &Qs[cc * 8]);
        gl_lds16(Kb + (size_t)(b * Ss + c0 + row) * Hh + h * HDd + sg, &Ks[cc * 8]);
    }
    __syncthreads();

    f32x4 acc[4][4] = {};
    #pragma unroll
    for (int kk = 0; kk < 2; ++kk) {
        const int s = kk * 4 + lg;
        bf16x8 kf[4], qf[4];
        #pragma unroll
        for (int m = 0; m < 4; ++m) kf[m] = ldfrag(Ks, wm + m * 16 + l15, s);
        #pragma unroll
        for (int n = 0; n < 4; ++n) qf[n] = ldfrag(Qs, wn + n * 16 + l15, s);
        #pragma unroll
        for (int m = 0; m < 4; ++m)
            #pragma unroll
            for (int n = 0; n < 4; ++n)
                acc[m][n] = __builtin_amdgcn_mfma_f32_16x16x32_bf16(
                    kf[m], qf[n], acc[m][n], 0, 0, 0);
    }

    #pragma unroll
    for (int n = 0; n < 4; ++n) {
        const int q = q0 + wn + n * 16 + l15;
        const float mv = mask[b * Ss + q];
        float* orow = out + ((size_t)(b * Ss + q) * NHh + h) * Ss;
        #pragma unroll
        for (int m = 0; m < 4; ++m) {
            const int kb = c0 + wm + m * 16 + lg * 4;
            float4 o;
            float v0 = acc[m][n][0] * 0.125f + mv;
            float v1 = acc[m][n][1] * 0.125f + mv;
            float v2 = acc[m][n][2] * 0.125f + mv;
            float v3 = acc[m][n][3] * 0.125f + mv;
            o.x = v0 > 0.f ? v0 : 0.f;
            o.y = v1 > 0.f ? v1 : 0.f;
            o.z = v2 > 0.f ? v2 : 0.f;
            o.w = v3 > 0.f ? v3 : 0.f;
            *(float4*)&orow[kb] = o;
        }
    }
}

// ---------------------------------------------------------------------------
extern "C" void kernel_launch(void* const* d_in, const int* in_sizes, int n_in,
                              void* d_out, int out_size, void* d_ws, size_t ws_size,
                              hipStream_t stream) {
    const float* hs   = (const float*)d_in[0];
    const float* mask = (const float*)d_in[1];
    // d_in[2] = input_ids (unused), d_in[3] = ngram (unused)
    const float* Wq = (const float*)d_in[4];
    const float* bq = (const float*)d_in[5];
    const float* Wk = (const float*)d_in[6];
    const float* bk = (const float*)d_in[7];
    float* out = (float*)d_out;

    // Workspace layout (bf16 elements):
    unsigned short* Qb  = (unsigned short*)d_ws;   // 4096*768
    unsigned short* Kb  = Qb  + 3145728;
    unsigned short* hsb = Kb  + 3145728;
    unsigned short* Wqb = hsb + 3145728;           // 768*768
    unsigned short* Wkb = Wqb + 589824;

    cast_kernel<<<2112, 256, 0, stream>>>(hs, Wq, Wk, hsb, Wqb, Wkb);
    proj_kernel<<<dim3(64, 6, 2), 256, 0, stream>>>(hsb, Wqb, Wkb, bq, bk, Qb, Kb);
    score_kernel<<<6144, 256, 0, stream>>>(Qb, Kb, mask, out);
}

// Round 4
// 128.741 us; speedup vs baseline: 1.0393x; 1.0393x over previous
//
#include <hip/hip_runtime.h>
#include <hip/hip_bf16.h>
#include <stdint.h>

// Problem constants
#define Bb  2
#define Ss  2048
#define Hh  768
#define NHh 12
#define HDd 64

typedef short bf16x8 __attribute__((ext_vector_type(8)));
typedef float f32x4  __attribute__((ext_vector_type(4)));
typedef unsigned short u16x4 __attribute__((ext_vector_type(4)));

// f32 -> bf16 round-to-nearest-even
__device__ __forceinline__ unsigned short f2bf(float x) {
    union { float f; unsigned int u; } v; v.f = x;
    unsigned int r = v.u + 0x7fffu + ((v.u >> 16) & 1u);
    return (unsigned short)(r >> 16);
}

// async global->LDS, 16B per lane (LDS dest = wave-uniform base + lane*16)
__device__ __forceinline__ void gl_lds16(const unsigned short* g, unsigned short* l) {
    __builtin_amdgcn_global_load_lds(
        (const __attribute__((address_space(1))) unsigned int*)g,
        (__attribute__((address_space(3))) unsigned int*)l, 16, 0, 0);
}

// Rows are 64 bf16 (128B = 8 chunks of 16B). Staging pre-swizzles the global
// source chunk (seg ^ (row&7)); reading slot s^(row&7) returns global chunk s
// and spreads 16 row-stride lanes across 8 chunk slots -> 2-way banks (free).
__device__ __forceinline__ bf16x8 ldfrag(const unsigned short* lds, int row, int s) {
    return *(const bf16x8*)&lds[(row << 6) + ((s ^ (row & 7)) << 3)];
}

// ---------------------------------------------------------------------------
// Cast hs [4096x768], Wq [768x768], Wk [768x768] f32 -> bf16.
// ---------------------------------------------------------------------------
__global__ __launch_bounds__(256)
void cast_kernel(const float* __restrict__ hs, const float* __restrict__ Wq,
                 const float* __restrict__ Wk,
                 unsigned short* __restrict__ hsb, unsigned short* __restrict__ Wqb,
                 unsigned short* __restrict__ Wkb)
{
    int cid = blockIdx.x * 256 + threadIdx.x;      // 0 .. 540671
    const float* src; unsigned short* dst; int base;
    if (cid < 393216)      { src = hs; dst = hsb; base = cid; }
    else if (cid < 466944) { src = Wq; dst = Wqb; base = cid - 393216; }
    else                   { src = Wk; dst = Wkb; base = cid - 466944; }
    float4 a0 = ((const float4*)src)[(size_t)base * 2];
    float4 a1 = ((const float4*)src)[(size_t)base * 2 + 1];
    bf16x8 v;
    v[0] = (short)f2bf(a0.x); v[1] = (short)f2bf(a0.y);
    v[2] = (short)f2bf(a0.z); v[3] = (short)f2bf(a0.w);
    v[4] = (short)f2bf(a1.x); v[5] = (short)f2bf(a1.y);
    v[6] = (short)f2bf(a1.z); v[7] = (short)f2bf(a1.w);
    ((bf16x8*)dst)[base] = v;
}

// ---------------------------------------------------------------------------
// K projection only: Kb[m, n] = sum_k hsb[m,k]*Wk[n,k] + bk[n]  (bf16 out).
// 64x64 tiles -> grid (64, 12) = 768 blocks = exactly 3/CU.
// Wave w owns out rows w*16..w*16+15; acc[4] covers the 64 out cols.
// ---------------------------------------------------------------------------
__global__ __launch_bounds__(256)
void kproj_kernel(const unsigned short* __restrict__ hsb,
                  const unsigned short* __restrict__ Wkb,
                  const float* __restrict__ bk,
                  unsigned short* __restrict__ Kb)
{
    const int m0 = blockIdx.x * 64;                // hs-row tile (out rows)
    const int n0 = blockIdx.y * 64;                // Wk-row tile (out cols)

    __shared__ unsigned short As[64 * 64];         // hs rows  [row][k]
    __shared__ unsigned short Bs[64 * 64];         // Wk rows  [row][k]

    const int tid  = threadIdx.x;
    const int lane = tid & 63;
    const int w    = tid >> 6;
    const int lg   = lane >> 4;
    const int l15  = lane & 15;
    const int sr   = w * 16 + l15;                 // lane's out row in tile

    f32x4 acc[4] = {};

    for (int k0 = 0; k0 < Hh; k0 += 64) {
        #pragma unroll
        for (int i = 0; i < 2; ++i) {
            int cc = i * 256 + tid, row = cc >> 3, seg = cc & 7;
            int sg = (seg ^ (row & 7)) << 3;
            gl_lds16(hsb + (size_t)(m0 + row) * Hh + k0 + sg, &As[cc * 8]);
            gl_lds16(Wkb + (size_t)(n0 + row) * Hh + k0 + sg, &Bs[cc * 8]);
        }
        __syncthreads();
        #pragma unroll
        for (int kk = 0; kk < 2; ++kk) {
            const int s = kk * 4 + lg;
            bf16x8 hf = ldfrag(As, sr, s);
            #pragma unroll
            for (int i = 0; i < 4; ++i) {
                bf16x8 wf = ldfrag(Bs, i * 16 + l15, s);
                acc[i] = __builtin_amdgcn_mfma_f32_16x16x32_bf16(wf, hf, acc[i], 0, 0, 0);
            }
        }
        __syncthreads();
    }

    #pragma unroll
    for (int i = 0; i < 4; ++i) {
        const int nb = n0 + i * 16 + lg * 4;
        const float4 bv = *(const float4*)&bk[nb];
        u16x4 o;
        o[0] = f2bf(acc[i][0] + bv.x); o[1] = f2bf(acc[i][1] + bv.y);
        o[2] = f2bf(acc[i][2] + bv.z); o[3] = f2bf(acc[i][3] + bv.w);
        *(u16x4*)&Kb[(size_t)(m0 + sr) * Hh + nb] = o;
    }
}

// ---------------------------------------------------------------------------
// Fused Q-projection + scores. One block per (b, h, 64-row q-strip):
//   Phase 1: Q[q,d] = sum_k hsb[q,k]*Wq[h*64+d,k] + bq  -> bf16 in LDS (Qs).
//   Phase 2: stream 32 K-chunks (64 rows x 64 d) double-buffered;
//            out[b,q,h,k] = relu(QK/8 + mask[b,q]); float4 stores,
//            256B contiguous per row per chunk.
// Q never round-trips through global; Q-proj overlaps the machine's write
// drain at the block level. 768 blocks = 3/CU.
// ---------------------------------------------------------------------------
__global__ __launch_bounds__(256)
void fused_kernel(const unsigned short* __restrict__ hsb,
                  const unsigned short* __restrict__ Wqb,
                  const float* __restrict__ bq,
                  const unsigned short* __restrict__ Kb,
                  const float* __restrict__ mask,
                  float* __restrict__ out)
{
    const int gid   = blockIdx.x;                  // 0..767
    const int bh    = gid >> 5;                    // 0..23
    const int strip = gid & 31;
    const int b = bh / NHh, h = bh % NHh;
    const int q0 = strip * 64;

    __shared__ unsigned short Hs[64 * 64];         // hs strip k-chunk   8KB
    __shared__ unsigned short Ws[64 * 64];         // Wq slice k-chunk   8KB
    __shared__ unsigned short Qs[64 * 64];         // projected Q strip  8KB
    __shared__ unsigned short Ks[2][64 * 64];      // K double buffer   16KB

    const int tid  = threadIdx.x;
    const int lane = tid & 63;
    const int w    = tid >> 6;
    const int lg   = lane >> 4;
    const int l15  = lane & 15;
    const int qr   = w * 16 + l15;                 // lane's q row in strip

    // ---- Phase 1: project the Q strip ----
    f32x4 qacc[4] = {};
    for (int k0 = 0; k0 < Hh; k0 += 64) {
        #pragma unroll
        for (int i = 0; i < 2; ++i) {
            int cc = i * 256 + tid, row = cc >> 3, seg = cc & 7;
            int sg = (seg ^ (row & 7)) << 3;
            gl_lds16(hsb + (size_t)(b * Ss + q0 + row) * Hh + k0 + sg, &Hs[cc * 8]);
            gl_lds16(Wqb + (size_t)(h * HDd + row) * Hh + k0 + sg, &Ws[cc * 8]);
        }
        __syncthreads();
        #pragma unroll
        for (int kk = 0; kk < 2; ++kk) {
            const int s = kk * 4 + lg;
            bf16x8 hf = ldfrag(Hs, qr, s);
            #pragma unroll
            for (int i = 0; i < 4; ++i) {
                bf16x8 wf = ldfrag(Ws, i * 16 + l15, s);
                qacc[i] = __builtin_amdgcn_mfma_f32_16x16x32_bf16(wf, hf, qacc[i], 0, 0, 0);
            }
        }
        __syncthreads();
    }

    // Park Q (bias-added, bf16) in Qs with the same chunk-XOR swizzle.
    #pragma unroll
    for (int i = 0; i < 4; ++i) {
        const int d0 = i * 16 + lg * 4;
        const float4 bv = *(const float4*)&bq[h * HDd + d0];
        u16x4 o;
        o[0] = f2bf(qacc[i][0] + bv.x); o[1] = f2bf(qacc[i][1] + bv.y);
        o[2] = f2bf(qacc[i][2] + bv.z); o[3] = f2bf(qacc[i][3] + bv.w);
        const int c = (d0 >> 3) ^ (qr & 7);
        *(u16x4*)&Qs[qr * 64 + c * 8 + (d0 & 7)] = o;
    }
    __syncthreads();

    // ---- Phase 2: stream K chunks ----
    const float mv = mask[b * Ss + q0 + qr];
    float* orow = out + ((size_t)(b * Ss + q0 + qr) * NHh + h) * Ss;

    bf16x8 qf0 = ldfrag(Qs, qr, lg);               // kk = 0 fragment
    bf16x8 qf1 = ldfrag(Qs, qr, 4 + lg);           // kk = 1 fragment

    // prologue: stage chunk 0
    #pragma unroll
    for (int i = 0; i < 2; ++i) {
        int cc = i * 256 + tid, row = cc >> 3, seg = cc & 7;
        gl_lds16(Kb + (size_t)(b * Ss + row) * Hh + h * HDd + ((seg ^ (row & 7)) << 3),
                 &Ks[0][cc * 8]);
    }
    __syncthreads();

    for (int ct = 0; ct < 32; ++ct) {
        const int cur = ct & 1;
        if (ct + 1 < 32) {                          // prefetch next chunk
            #pragma unroll
            for (int i = 0; i < 2; ++i) {
                int cc = i * 256 + tid, row = cc >> 3, seg = cc & 7;
                gl_lds16(Kb + (size_t)(b * Ss + (ct + 1) * 64 + row) * Hh + h * HDd
                             + ((seg ^ (row & 7)) << 3),
                         &Ks[cur ^ 1][cc * 8]);
            }
        }

        f32x4 acc[4] = {};
        #pragma unroll
        for (int m = 0; m < 4; ++m) {
            bf16x8 kf0 = ldfrag(Ks[cur], m * 16 + l15, lg);
            bf16x8 kf1 = ldfrag(Ks[cur], m * 16 + l15, 4 + lg);
            acc[m] = __builtin_amdgcn_mfma_f32_16x16x32_bf16(kf0, qf0, acc[m], 0, 0, 0);
            acc[m] = __builtin_amdgcn_mfma_f32_16x16x32_bf16(kf1, qf1, acc[m], 0, 0, 0);
        }

        #pragma unroll
        for (int m = 0; m < 4; ++m) {
            float v0 = acc[m][0] * 0.125f + mv;
            float v1 = acc[m][1] * 0.125f + mv;
            float v2 = acc[m][2] * 0.125f + mv;
            float v3 = acc[m][3] * 0.125f + mv;
            float4 o;
            o.x = v0 > 0.f ? v0 : 0.f;
            o.y = v1 > 0.f ? v1 : 0.f;
            o.z = v2 > 0.f ? v2 : 0.f;
            o.w = v3 > 0.f ? v3 : 0.f;
            *(float4*)&orow[ct * 64 + m * 16 + lg * 4] = o;
        }
        __syncthreads();   // all waves done with Ks[cur]; prefetch drained
    }
}

// ---------------------------------------------------------------------------
extern "C" void kernel_launch(void* const* d_in, const int* in_sizes, int n_in,
                              void* d_out, int out_size, void* d_ws, size_t ws_size,
                              hipStream_t stream) {
    const float* hs   = (const float*)d_in[0];
    const float* mask = (const float*)d_in[1];
    // d_in[2] = input_ids (unused), d_in[3] = ngram (unused)
    const float* Wq = (const float*)d_in[4];
    const float* bq = (const float*)d_in[5];
    const float* Wk = (const float*)d_in[6];
    const float* bk = (const float*)d_in[7];
    float* out = (float*)d_out;

    // Workspace layout (bf16 elements):
    unsigned short* Kb  = (unsigned short*)d_ws;   // 4096*768
    unsigned short* hsb = Kb  + 3145728;           // 4096*768
    unsigned short* Wqb = hsb + 3145728;           // 768*768
    unsigned short* Wkb = Wqb + 589824;            // 768*768

    cast_kernel<<<2112, 256, 0, stream>>>(hs, Wq, Wk, hsb, Wqb, Wkb);
    kproj_kernel<<<dim3(64, 12), 256, 0, stream>>>(hsb, Wkb, bk, Kb);
    fused_kernel<<<768, 256, 0, stream>>>(hsb, Wqb, bq, Kb, mask, out);
}